// Round 2
// baseline (3392.587 us; speedup 1.0000x reference)
//
#include <hip/hip_runtime.h>
#include <math.h>

#define HIDDEN 1024
#define NSEQ   512
#define BATCH  32
#define NTOK   (BATCH * NSEQ)      // 16384
#define EDIM   2048
#define SDIM   128
#define UVN    (2 * EDIM + SDIM)   // 4224

// ---------------------------------------------------------------------------
// Rope sin/cos table in double precision: angle = i * 10000^(j/64),
// i in [0,512), j in [0,64). fp32 angles lose ~0.5 rad at i*freq ~ 4e6, so
// compute in f64 to track the numpy reference.
// ---------------------------------------------------------------------------
__global__ __launch_bounds__(64) void tab_kernel(float* __restrict__ sin_t,
                                                 float* __restrict__ cos_t) {
    int i = blockIdx.x;
    int j = threadIdx.x;
    double inv = pow(10000.0, (double)j / 64.0);
    double ang = (double)i * inv;
    sin_t[i * 64 + j] = (float)sin(ang);
    cos_t[i * 64 + j] = (float)cos(ang);
}

// ---------------------------------------------------------------------------
// LayerNorm: one block per token, 256 threads, float4 per thread (1024 elems).
// Two-pass (mean, then centered var) for accuracy.
// ---------------------------------------------------------------------------
__global__ __launch_bounds__(256) void ln_kernel(const float* __restrict__ x,
                                                 const float* __restrict__ g,
                                                 const float* __restrict__ b,
                                                 float* __restrict__ xn) {
    const size_t t = blockIdx.x;
    const int tid = threadIdx.x;
    const float4 v = ((const float4*)(x + t * HIDDEN))[tid];
    float s = v.x + v.y + v.z + v.w;
#pragma unroll
    for (int off = 32; off > 0; off >>= 1) s += __shfl_down(s, off);
    __shared__ float red[4];
    const int wid = tid >> 6, lane = tid & 63;
    if (lane == 0) red[wid] = s;
    __syncthreads();
    const float mean = (red[0] + red[1] + red[2] + red[3]) * (1.0f / HIDDEN);
    __syncthreads();
    const float dx = v.x - mean, dy = v.y - mean, dz = v.z - mean, dw = v.w - mean;
    float s2 = dx * dx + dy * dy + dz * dz + dw * dw;
#pragma unroll
    for (int off = 32; off > 0; off >>= 1) s2 += __shfl_down(s2, off);
    if (lane == 0) red[wid] = s2;
    __syncthreads();
    const float var = (red[0] + red[1] + red[2] + red[3]) * (1.0f / HIDDEN);
    const float rs = rsqrtf(var + 1e-5f);
    const float4 gv = ((const float4*)g)[tid];
    const float4 bv = ((const float4*)b)[tid];
    float4 o;
    o.x = dx * rs * gv.x + bv.x;
    o.y = dy * rs * gv.y + bv.y;
    o.z = dz * rs * gv.z + bv.z;
    o.w = dw * rs * gv.w + bv.w;
    ((float4*)(xn + t * HIDDEN))[tid] = o;
}

// ---------------------------------------------------------------------------
// GEMM1: uv = silu(xn @ uv_w + uv_b); split into U | V | BASE.
// 64x64 tile, BK=16, 256 thr, 4x4 acc/thread. M=R N=4224 K=1024.
// ---------------------------------------------------------------------------
__global__ __launch_bounds__(256) void gemm_uv(const float* __restrict__ A,
                                               const float* __restrict__ B,
                                               const float* __restrict__ bias,
                                               float* __restrict__ U,
                                               float* __restrict__ V,
                                               float* __restrict__ BASE) {
    __shared__ float As[16][68];
    __shared__ float Bs[16][64];
    const int tid = threadIdx.x;
    const int tx = tid & 15, ty = tid >> 4;
    const int arow = tid >> 2, acol = (tid & 3) << 2;
    const int brow = tid >> 4, bcol = (tid & 15) << 2;
    const int n0 = blockIdx.x * 64, m0 = blockIdx.y * 64;
    float acc[4][4] = {};
    for (int k0 = 0; k0 < HIDDEN; k0 += 16) {
        float4 av = *(const float4*)(A + (size_t)(m0 + arow) * HIDDEN + (k0 + acol));
        float4 bv = *(const float4*)(B + (size_t)(k0 + brow) * UVN + (n0 + bcol));
        As[acol + 0][arow] = av.x; As[acol + 1][arow] = av.y;
        As[acol + 2][arow] = av.z; As[acol + 3][arow] = av.w;
        *(float4*)&Bs[brow][bcol] = bv;
        __syncthreads();
#pragma unroll
        for (int kk = 0; kk < 16; ++kk) {
            const float4 a4 = *(const float4*)&As[kk][ty << 2];
            const float4 b4 = *(const float4*)&Bs[kk][tx << 2];
            const float a[4] = {a4.x, a4.y, a4.z, a4.w};
            const float bb[4] = {b4.x, b4.y, b4.z, b4.w};
#pragma unroll
            for (int i = 0; i < 4; ++i)
#pragma unroll
                for (int j = 0; j < 4; ++j)
                    acc[i][j] = fmaf(a[i], bb[j], acc[i][j]);
        }
        __syncthreads();
    }
#pragma unroll
    for (int i = 0; i < 4; ++i) {
        const size_t m = m0 + (ty << 2) + i;
#pragma unroll
        for (int j = 0; j < 4; ++j) {
            const int n = n0 + (tx << 2) + j;
            float val = acc[i][j] + bias[n];
            val = val / (1.0f + expf(-val));   // silu
            if (n < EDIM)            U[m * EDIM + n] = val;
            else if (n < 2 * EDIM)   V[m * EDIM + (n - EDIM)] = val;
            else                     BASE[m * SDIM + (n - 2 * EDIM)] = val;
        }
    }
}

// ---------------------------------------------------------------------------
// Rope: base(r,128) -> q,k(r,128) with per-channel gamma/beta then rotate.
// ---------------------------------------------------------------------------
__global__ __launch_bounds__(128) void rope_kernel(const float* __restrict__ base,
                                                   const float* __restrict__ gamma,
                                                   const float* __restrict__ beta,
                                                   const float* __restrict__ sin_t,
                                                   const float* __restrict__ cos_t,
                                                   float* __restrict__ q,
                                                   float* __restrict__ k) {
    const size_t t = blockIdx.x;
    const int d = threadIdx.x;
    const int pos = (int)(t & (NSEQ - 1));
    __shared__ float vq[128], vk[128];
    const float bval = base[t * SDIM + d];
    vq[d] = bval * gamma[d] + beta[d];
    vk[d] = bval * gamma[SDIM + d] + beta[SDIM + d];
    __syncthreads();
    const int h = d & 63;
    const float sn = sin_t[pos * 64 + h];
    const float cs = cos_t[pos * 64 + h];
    float oq, ok;
    if (d < 64) {
        oq = vq[d] * cs - vq[d + 64] * sn;
        ok = vk[d] * cs - vk[d + 64] * sn;
    } else {
        oq = vq[d] * cs + vq[d - 64] * sn;
        ok = vk[d] * cs + vk[d - 64] * sn;
    }
    q[t * SDIM + d] = oq;
    k[t * SDIM + d] = ok;
}

// ---------------------------------------------------------------------------
// QK^T per batch (NT), then squared-relu kernel with bias w[511+j-i] and mask.
// M=N=512, K=128 per batch. blockIdx.z = chunk-local batch.
// ---------------------------------------------------------------------------
__global__ __launch_bounds__(256) void gemm_qk(const float* __restrict__ q,
                                               const float* __restrict__ k,
                                               const float* __restrict__ mask,
                                               const float* __restrict__ w,
                                               float* __restrict__ km) {
    __shared__ float As[16][68];
    __shared__ float Bs[16][68];
    const int b = blockIdx.z;
    const float* A = q + (size_t)b * NSEQ * SDIM;
    const float* B = k + (size_t)b * NSEQ * SDIM;
    const int tid = threadIdx.x;
    const int tx = tid & 15, ty = tid >> 4;
    const int arow = tid >> 2, acol = (tid & 3) << 2;
    const int n0 = blockIdx.x * 64, m0 = blockIdx.y * 64;
    float acc[4][4] = {};
    for (int k0 = 0; k0 < SDIM; k0 += 16) {
        float4 av = *(const float4*)(A + (size_t)(m0 + arow) * SDIM + (k0 + acol));
        float4 bv = *(const float4*)(B + (size_t)(n0 + arow) * SDIM + (k0 + acol));
        As[acol + 0][arow] = av.x; As[acol + 1][arow] = av.y;
        As[acol + 2][arow] = av.z; As[acol + 3][arow] = av.w;
        Bs[acol + 0][arow] = bv.x; Bs[acol + 1][arow] = bv.y;
        Bs[acol + 2][arow] = bv.z; Bs[acol + 3][arow] = bv.w;
        __syncthreads();
#pragma unroll
        for (int kk = 0; kk < 16; ++kk) {
            const float4 a4 = *(const float4*)&As[kk][ty << 2];
            const float4 b4 = *(const float4*)&Bs[kk][tx << 2];
            const float a[4] = {a4.x, a4.y, a4.z, a4.w};
            const float bb[4] = {b4.x, b4.y, b4.z, b4.w};
#pragma unroll
            for (int i = 0; i < 4; ++i)
#pragma unroll
                for (int j = 0; j < 4; ++j)
                    acc[i][j] = fmaf(a[i], bb[j], acc[i][j]);
        }
        __syncthreads();
    }
    const float inv512 = 1.0f / 512.0f;
#pragma unroll
    for (int i = 0; i < 4; ++i) {
        const int ii = m0 + (ty << 2) + i;
#pragma unroll
        for (int j = 0; j < 4; ++j) {
            const int jj = n0 + (tx << 2) + j;
            const float mterm = (1.0f - mask[b * NSEQ + jj]) * -1e12f;
            float val = (acc[i][j] + mterm) * inv512 + w[511 + jj - ii];
            val = fmaxf(val, 0.0f);
            km[(size_t)b * NSEQ * NSEQ + (size_t)ii * NSEQ + jj] = val * val;
        }
    }
}

// ---------------------------------------------------------------------------
// kernel @ V per batch (NN), gated by u in epilogue (writes over u's buffer).
// M=512 N=2048 K=512 per batch.
// ---------------------------------------------------------------------------
__global__ __launch_bounds__(256) void gemm_pv(const float* __restrict__ km,
                                               const float* __restrict__ v,
                                               const float* __restrict__ u,
                                               float* __restrict__ gated) {
    __shared__ float As[16][68];
    __shared__ float Bs[16][64];
    const int b = blockIdx.z;
    const float* A = km + (size_t)b * NSEQ * NSEQ;
    const float* B = v + (size_t)b * NSEQ * EDIM;
    const int tid = threadIdx.x;
    const int tx = tid & 15, ty = tid >> 4;
    const int arow = tid >> 2, acol = (tid & 3) << 2;
    const int brow = tid >> 4, bcol = (tid & 15) << 2;
    const int n0 = blockIdx.x * 64, m0 = blockIdx.y * 64;
    float acc[4][4] = {};
    for (int k0 = 0; k0 < NSEQ; k0 += 16) {
        float4 av = *(const float4*)(A + (size_t)(m0 + arow) * NSEQ + (k0 + acol));
        float4 bv = *(const float4*)(B + (size_t)(k0 + brow) * EDIM + (n0 + bcol));
        As[acol + 0][arow] = av.x; As[acol + 1][arow] = av.y;
        As[acol + 2][arow] = av.z; As[acol + 3][arow] = av.w;
        *(float4*)&Bs[brow][bcol] = bv;
        __syncthreads();
#pragma unroll
        for (int kk = 0; kk < 16; ++kk) {
            const float4 a4 = *(const float4*)&As[kk][ty << 2];
            const float4 b4 = *(const float4*)&Bs[kk][tx << 2];
            const float a[4] = {a4.x, a4.y, a4.z, a4.w};
            const float bb[4] = {b4.x, b4.y, b4.z, b4.w};
#pragma unroll
            for (int i = 0; i < 4; ++i)
#pragma unroll
                for (int j = 0; j < 4; ++j)
                    acc[i][j] = fmaf(a[i], bb[j], acc[i][j]);
        }
        __syncthreads();
    }
#pragma unroll
    for (int i = 0; i < 4; ++i) {
        const size_t m = (size_t)b * NSEQ + m0 + (ty << 2) + i;
#pragma unroll
        for (int j = 0; j < 4; ++j) {
            const int n = n0 + (tx << 2) + j;
            gated[m * EDIM + n] = u[m * EDIM + n] * acc[i][j];
        }
    }
}

// ---------------------------------------------------------------------------
// GEMM2: out = gated @ o_w + o_b + x. M=R N=1024 K=2048.
// ---------------------------------------------------------------------------
__global__ __launch_bounds__(256) void gemm_out(const float* __restrict__ A,
                                                const float* __restrict__ B,
                                                const float* __restrict__ ob,
                                                const float* __restrict__ x,
                                                float* __restrict__ out) {
    __shared__ float As[16][68];
    __shared__ float Bs[16][64];
    const int tid = threadIdx.x;
    const int tx = tid & 15, ty = tid >> 4;
    const int arow = tid >> 2, acol = (tid & 3) << 2;
    const int brow = tid >> 4, bcol = (tid & 15) << 2;
    const int n0 = blockIdx.x * 64, m0 = blockIdx.y * 64;
    float acc[4][4] = {};
    for (int k0 = 0; k0 < EDIM; k0 += 16) {
        float4 av = *(const float4*)(A + (size_t)(m0 + arow) * EDIM + (k0 + acol));
        float4 bv = *(const float4*)(B + (size_t)(k0 + brow) * HIDDEN + (n0 + bcol));
        As[acol + 0][arow] = av.x; As[acol + 1][arow] = av.y;
        As[acol + 2][arow] = av.z; As[acol + 3][arow] = av.w;
        *(float4*)&Bs[brow][bcol] = bv;
        __syncthreads();
#pragma unroll
        for (int kk = 0; kk < 16; ++kk) {
            const float4 a4 = *(const float4*)&As[kk][ty << 2];
            const float4 b4 = *(const float4*)&Bs[kk][tx << 2];
            const float a[4] = {a4.x, a4.y, a4.z, a4.w};
            const float bb[4] = {b4.x, b4.y, b4.z, b4.w};
#pragma unroll
            for (int i = 0; i < 4; ++i)
#pragma unroll
                for (int j = 0; j < 4; ++j)
                    acc[i][j] = fmaf(a[i], bb[j], acc[i][j]);
        }
        __syncthreads();
    }
#pragma unroll
    for (int i = 0; i < 4; ++i) {
        const size_t m = m0 + (ty << 2) + i;
#pragma unroll
        for (int j = 0; j < 4; ++j) {
            const int n = n0 + (tx << 2) + j;
            out[m * HIDDEN + n] = acc[i][j] + ob[n] + x[m * HIDDEN + n];
        }
    }
}

// ---------------------------------------------------------------------------
// Workspace: adaptive batch-chunking. Per chunk of C batches (R = C*512 rows):
//   xn   : C*524288 floats   (dead after gemm_uv; q/k/km overlay here:
//                             q @ +0 (C*65536), k @ +C*65536, km @ +C*131072,
//                             km needs C*262144 -> ends at C*393216 < C*524288)
//   u    : C*1048576         (gated written in-place)
//   v    : C*1048576
//   base : C*65536
//   sin/cos tables: 32768 each
// Total floats = C*2686976 + 65536  ->  C=32: 344 MB, 16: 172, 8: 86, 4: 43.
// C chosen as the largest power of two whose footprint fits ws_size
// (ws_size is constant across calls -> identical work every call).
// ---------------------------------------------------------------------------
extern "C" void kernel_launch(void* const* d_in, const int* in_sizes, int n_in,
                              void* d_out, int out_size, void* d_ws, size_t ws_size,
                              hipStream_t stream) {
    const float* x     = (const float*)d_in[0];
    const float* mask  = (const float*)d_in[1];
    const float* gamma = (const float*)d_in[2];
    const float* beta  = (const float*)d_in[3];
    const float* w     = (const float*)d_in[4];
    const float* uv_w  = (const float*)d_in[7];
    const float* uv_b  = (const float*)d_in[8];
    const float* o_w   = (const float*)d_in[9];
    const float* o_b   = (const float*)d_in[10];
    const float* ln_g  = (const float*)d_in[11];
    const float* ln_b  = (const float*)d_in[12];
    float* out = (float*)d_out;

    int C = 32;
    while (C > 1) {
        unsigned long long need = ((unsigned long long)C * 2686976ull + 65536ull) * 4ull;
        if (need <= (unsigned long long)ws_size) break;
        C >>= 1;
    }
    const int R = C * NSEQ;   // rows per chunk

    float* ws   = (float*)d_ws;
    float* xn   = ws;
    float* u    = xn + (size_t)C * 524288;
    float* v    = u + (size_t)C * 1048576;
    float* base = v + (size_t)C * 1048576;
    float* sint = base + (size_t)C * 65536;
    float* cost = sint + 32768;
    float* q    = xn;
    float* k    = xn + (size_t)C * 65536;
    float* km   = xn + (size_t)C * 131072;

    hipLaunchKernelGGL(tab_kernel, dim3(512), dim3(64), 0, stream, sint, cost);

    for (int b0 = 0; b0 < BATCH; b0 += C) {
        const float* xc  = x + (size_t)b0 * NSEQ * HIDDEN;
        float*       oc  = out + (size_t)b0 * NSEQ * HIDDEN;
        const float* mc  = mask + (size_t)b0 * NSEQ;
        hipLaunchKernelGGL(ln_kernel, dim3(R), dim3(256), 0, stream, xc, ln_g, ln_b, xn);
        hipLaunchKernelGGL(gemm_uv, dim3(66, R / 64), dim3(256), 0, stream, xn, uv_w, uv_b, u, v, base);
        hipLaunchKernelGGL(rope_kernel, dim3(R), dim3(128), 0, stream, base, gamma, beta, sint, cost, q, k);
        hipLaunchKernelGGL(gemm_qk, dim3(8, 8, C), dim3(256), 0, stream, q, k, mc, w, km);
        hipLaunchKernelGGL(gemm_pv, dim3(32, 8, C), dim3(256), 0, stream, km, v, u, u);
        hipLaunchKernelGGL(gemm_out, dim3(16, R / 64), dim3(256), 0, stream, u, o_w, o_b, xc, oc);
    }
}

// Round 4
// 604.811 us; speedup vs baseline: 5.6093x; 5.6093x over previous
//
#include <hip/hip_runtime.h>
#include <math.h>

#define HIDDEN 1024
#define NSEQ   512
#define BATCH  32
#define EDIM   2048
#define SDIM   128
#define UVN    (2 * EDIM + SDIM)   // 4224

using short8  = __attribute__((ext_vector_type(8))) short;
using float4x = __attribute__((ext_vector_type(4))) float;

__device__ __forceinline__ ushort f2bf(float f) {
    unsigned u = __float_as_uint(f);
    u += 0x7FFFu + ((u >> 16) & 1u);   // RNE
    return (ushort)(u >> 16);
}
__device__ __forceinline__ float bf2f(ushort h) {
    return __uint_as_float(((unsigned)h) << 16);
}

// global->LDS direct copy, 16B per lane. LDS dest = wave-uniform base + lane*16.
#define ASYNC16(gp, lp) __builtin_amdgcn_global_load_lds( \
    (const __attribute__((address_space(1))) unsigned int*)(unsigned long long)(const void*)(gp), \
    (__attribute__((address_space(3))) unsigned int*)(unsigned int)(unsigned long long)(const void*)(lp), \
    16, 0, 0)

// ---------------------------------------------------------------------------
// Rope sin/cos table in double precision (fp32 angles lose accuracy at
// i*freq ~ 4e6; f64 tracks the numpy reference).
// ---------------------------------------------------------------------------
__global__ __launch_bounds__(64) void tab_kernel(float* __restrict__ sin_t,
                                                 float* __restrict__ cos_t) {
    int i = blockIdx.x;
    int j = threadIdx.x;
    double inv = pow(10000.0, (double)j / 64.0);
    double ang = (double)i * inv;
    sin_t[i * 64 + j] = (float)sin(ang);
    cos_t[i * 64 + j] = (float)cos(ang);
}

// ---------------------------------------------------------------------------
// Transpose + fp32->bf16: src[R][Cc] fp32 -> dst[Cc][R] bf16.
// ---------------------------------------------------------------------------
__global__ __launch_bounds__(256) void transpose_f32_bf16(const float* __restrict__ src,
                                                          ushort* __restrict__ dst,
                                                          int R, int Cc) {
    __shared__ float tile[32][33];
    const int bx = blockIdx.x;            // col tile of src
    const int by = blockIdx.y;            // row tile of src
    const int lx = threadIdx.x & 31;
    const int gy = threadIdx.x >> 5;      // 0..7
#pragma unroll
    for (int i = 0; i < 4; ++i) {
        int r = by * 32 + gy + i * 8;
        tile[gy + i * 8][lx] = src[(size_t)r * Cc + bx * 32 + lx];
    }
    __syncthreads();
#pragma unroll
    for (int i = 0; i < 4; ++i) {
        int c = bx * 32 + gy + i * 8;
        dst[(size_t)c * R + by * 32 + lx] = f2bf(tile[lx][gy + i * 8]);
    }
}

// ---------------------------------------------------------------------------
// LayerNorm: one block per token, 256 threads, float4/thread. bf16 output.
// ---------------------------------------------------------------------------
__global__ __launch_bounds__(256) void ln_kernel(const float* __restrict__ x,
                                                 const float* __restrict__ g,
                                                 const float* __restrict__ b,
                                                 ushort* __restrict__ xn) {
    const size_t t = blockIdx.x;
    const int tid = threadIdx.x;
    const float4 v = ((const float4*)(x + t * HIDDEN))[tid];
    float s = v.x + v.y + v.z + v.w;
#pragma unroll
    for (int off = 32; off > 0; off >>= 1) s += __shfl_down(s, off);
    __shared__ float red[4];
    const int wid = tid >> 6, lane = tid & 63;
    if (lane == 0) red[wid] = s;
    __syncthreads();
    const float mean = (red[0] + red[1] + red[2] + red[3]) * (1.0f / HIDDEN);
    __syncthreads();
    const float dx = v.x - mean, dy = v.y - mean, dz = v.z - mean, dw = v.w - mean;
    float s2 = dx * dx + dy * dy + dz * dz + dw * dw;
#pragma unroll
    for (int off = 32; off > 0; off >>= 1) s2 += __shfl_down(s2, off);
    if (lane == 0) red[wid] = s2;
    __syncthreads();
    const float var = (red[0] + red[1] + red[2] + red[3]) * (1.0f / HIDDEN);
    const float rs = rsqrtf(var + 1e-5f);
    const float4 gv = ((const float4*)g)[tid];
    const float4 bv = ((const float4*)b)[tid];
    ushort4 o;
    o.x = f2bf(dx * rs * gv.x + bv.x);
    o.y = f2bf(dy * rs * gv.y + bv.y);
    o.z = f2bf(dz * rs * gv.z + bv.z);
    o.w = f2bf(dw * rs * gv.w + bv.w);
    ((ushort4*)(xn + t * HIDDEN))[tid] = o;
}

// ---------------------------------------------------------------------------
// MFMA GEMM core (m97 structure): C[128][128] tile, BK=32, 256 thr = 4 waves
// in a 2x2 grid, each wave 4x4 frags of mfma_f32_16x16x32_bf16.
// A: [M][K] bf16 row-major.  Bt: [N][K] bf16 row-major (B transposed).
// Staging: global_load_lds 16B/lane into contiguous LDS [128][32].
// ---------------------------------------------------------------------------
__device__ __forceinline__ void mfma_core_128(const ushort* __restrict__ A,
                                              const ushort* __restrict__ Bt,
                                              const int lda, const int ldb, const int K,
                                              const int m0, const int n0,
                                              ushort* As, ushort* Bs,
                                              float4x (&acc)[4][4]) {
    const int tid = threadIdx.x;
    const int l = tid & 63, w = tid >> 6;
    const int wm = (w & 1) << 6, wn = (w >> 1) << 6;

    // staging: 512 16B-chunks per tile; wave w owns chunks [w*128, w*128+128)
    const int c0 = w * 128 + l;
    const int r0 = c0 >> 2, kc0 = (c0 & 3) * 8;
    const int c1 = c0 + 64;
    const int r1 = c1 >> 2, kc1 = (c1 & 3) * 8;
    char* ldsA0 = (char*)As + (size_t)(w * 128) * 16;
    char* ldsA1 = ldsA0 + 1024;
    char* ldsB0 = (char*)Bs + (size_t)(w * 128) * 16;
    char* ldsB1 = ldsB0 + 1024;
    const ushort* gA0 = A + (size_t)(m0 + r0) * lda + kc0;
    const ushort* gA1 = A + (size_t)(m0 + r1) * lda + kc1;
    const ushort* gB0 = Bt + (size_t)(n0 + r0) * ldb + kc0;
    const ushort* gB1 = Bt + (size_t)(n0 + r1) * ldb + kc1;

    // fragment LDS element offsets
    const int lr = l & 15, lk = (l >> 4) * 8;
    int aoff[4], boff[4];
#pragma unroll
    for (int i = 0; i < 4; ++i) {
        aoff[i] = (wm + i * 16 + lr) * 32 + lk;
        boff[i] = (wn + i * 16 + lr) * 32 + lk;
    }

    for (int k0 = 0; k0 < K; k0 += 32) {
        __syncthreads();
        ASYNC16(gA0 + k0, ldsA0);
        ASYNC16(gA1 + k0, ldsA1);
        ASYNC16(gB0 + k0, ldsB0);
        ASYNC16(gB1 + k0, ldsB1);
        __syncthreads();
        short8 af[4], bfr[4];
#pragma unroll
        for (int i = 0; i < 4; ++i) af[i] = *(const short8*)(As + aoff[i]);
#pragma unroll
        for (int i = 0; i < 4; ++i) bfr[i] = *(const short8*)(Bs + boff[i]);
#pragma unroll
        for (int mi = 0; mi < 4; ++mi)
#pragma unroll
            for (int ni = 0; ni < 4; ++ni)
                acc[mi][ni] = __builtin_amdgcn_mfma_f32_16x16x32_bf16(
                    af[mi], bfr[ni], acc[mi][ni], 0, 0, 0);
    }
}

// C/D layout (verified m89/m91): col = lane&15, row = (lane>>4)*4 + reg.
template <typename F>
__device__ __forceinline__ void epilogue_loop(const float4x (&acc)[4][4],
                                              int m0, int n0, F body) {
    const int l = threadIdx.x & 63, w = threadIdx.x >> 6;
    const int wm = (w & 1) << 6, wn = (w >> 1) << 6;
    const int lrow = (l >> 4) << 2, lcol = l & 15;
#pragma unroll
    for (int mi = 0; mi < 4; ++mi)
#pragma unroll
        for (int ni = 0; ni < 4; ++ni)
#pragma unroll
            for (int r = 0; r < 4; ++r) {
                const int m = m0 + wm + mi * 16 + lrow + r;
                const int n = n0 + wn + ni * 16 + lcol;
                body(m, n, acc[mi][ni][r]);
            }
}

// ---------------------------------------------------------------------------
// GEMM1: uv = silu(xn @ uv_w + uv_b) -> U bf16 [m][2048], VT bf16 [b][2048][512],
// BASE fp32 [m][128]. n-tiles: 0..15 -> U, 16..31 -> V, 32 -> BASE.
// ---------------------------------------------------------------------------
__global__ __launch_bounds__(256) void gemm_uv_mfma(const ushort* __restrict__ A,
                                                    const ushort* __restrict__ Bt,
                                                    const float* __restrict__ bias,
                                                    ushort* __restrict__ U,
                                                    ushort* __restrict__ VT,
                                                    float* __restrict__ BASE) {
    __shared__ ushort As[128 * 32], Bs[128 * 32];
    float4x acc[4][4] = {};
    const int n0 = blockIdx.x * 128, m0 = blockIdx.y * 128;
    mfma_core_128(A, Bt, HIDDEN, HIDDEN, HIDDEN, m0, n0, As, Bs, acc);
    const int bx = blockIdx.x;
    if (bx < 16) {
        epilogue_loop(acc, m0, n0, [&](int m, int n, float aval) {
            float val = aval + bias[n];
            val = val / (1.0f + expf(-val));
            U[(size_t)m * EDIM + n] = f2bf(val);
        });
    } else if (bx < 32) {
        epilogue_loop(acc, m0, n0, [&](int m, int n, float aval) {
            float val = aval + bias[n];
            val = val / (1.0f + expf(-val));
            const int e = n - EDIM;
            const int b = m >> 9;
            const int s = m & (NSEQ - 1);
            VT[((size_t)b * EDIM + e) * NSEQ + s] = f2bf(val);
        });
    } else {
        epilogue_loop(acc, m0, n0, [&](int m, int n, float aval) {
            float val = aval + bias[n];
            val = val / (1.0f + expf(-val));
            BASE[(size_t)m * SDIM + (n - 2 * EDIM)] = val;
        });
    }
}

// ---------------------------------------------------------------------------
// Rope: base(r,128) -> q,k(r,128) fp32.
// ---------------------------------------------------------------------------
__global__ __launch_bounds__(128) void rope_kernel(const float* __restrict__ base,
                                                   const float* __restrict__ gamma,
                                                   const float* __restrict__ beta,
                                                   const float* __restrict__ sin_t,
                                                   const float* __restrict__ cos_t,
                                                   float* __restrict__ q,
                                                   float* __restrict__ k) {
    const size_t t = blockIdx.x;
    const int d = threadIdx.x;
    const int pos = (int)(t & (NSEQ - 1));
    __shared__ float vq[128], vk[128];
    const float bval = base[t * SDIM + d];
    vq[d] = bval * gamma[d] + beta[d];
    vk[d] = bval * gamma[SDIM + d] + beta[SDIM + d];
    __syncthreads();
    const int h = d & 63;
    const float sn = sin_t[pos * 64 + h];
    const float cs = cos_t[pos * 64 + h];
    float oq, ok;
    if (d < 64) {
        oq = vq[d] * cs - vq[d + 64] * sn;
        ok = vk[d] * cs - vk[d + 64] * sn;
    } else {
        oq = vq[d] * cs + vq[d - 64] * sn;
        ok = vk[d] * cs + vk[d - 64] * sn;
    }
    q[t * SDIM + d] = oq;
    k[t * SDIM + d] = ok;
}

// ---------------------------------------------------------------------------
// QK^T per batch (fp32 vector: only 4.3 GF; keeps the bias-dominated kernel
// matrix exact). Epilogue: squared-relu with w[511+j-i], mask; bf16 out.
// ---------------------------------------------------------------------------
__global__ __launch_bounds__(256) void gemm_qk(const float* __restrict__ q,
                                               const float* __restrict__ k,
                                               const float* __restrict__ mask,
                                               const float* __restrict__ w,
                                               ushort* __restrict__ km) {
    __shared__ float As[16][68];
    __shared__ float Bs[16][68];
    const int b = blockIdx.z;
    const float* A = q + (size_t)b * NSEQ * SDIM;
    const float* B = k + (size_t)b * NSEQ * SDIM;
    const int tid = threadIdx.x;
    const int tx = tid & 15, ty = tid >> 4;
    const int arow = tid >> 2, acol = (tid & 3) << 2;
    const int n0 = blockIdx.x * 64, m0 = blockIdx.y * 64;
    float acc[4][4] = {};
    for (int k0 = 0; k0 < SDIM; k0 += 16) {
        float4 av = *(const float4*)(A + (size_t)(m0 + arow) * SDIM + (k0 + acol));
        float4 bv = *(const float4*)(B + (size_t)(n0 + arow) * SDIM + (k0 + acol));
        As[acol + 0][arow] = av.x; As[acol + 1][arow] = av.y;
        As[acol + 2][arow] = av.z; As[acol + 3][arow] = av.w;
        Bs[acol + 0][arow] = bv.x; Bs[acol + 1][arow] = bv.y;
        Bs[acol + 2][arow] = bv.z; Bs[acol + 3][arow] = bv.w;
        __syncthreads();
#pragma unroll
        for (int kk = 0; kk < 16; ++kk) {
            const float4 a4 = *(const float4*)&As[kk][ty << 2];
            const float4 b4 = *(const float4*)&Bs[kk][tx << 2];
            const float a[4] = {a4.x, a4.y, a4.z, a4.w};
            const float bb[4] = {b4.x, b4.y, b4.z, b4.w};
#pragma unroll
            for (int i = 0; i < 4; ++i)
#pragma unroll
                for (int j = 0; j < 4; ++j)
                    acc[i][j] = fmaf(a[i], bb[j], acc[i][j]);
        }
        __syncthreads();
    }
    const float inv512 = 1.0f / 512.0f;
#pragma unroll
    for (int i = 0; i < 4; ++i) {
        const int ii = m0 + (ty << 2) + i;
#pragma unroll
        for (int j = 0; j < 4; ++j) {
            const int jj = n0 + (tx << 2) + j;
            const float mterm = (1.0f - mask[b * NSEQ + jj]) * -1e12f;
            float val = (acc[i][j] + mterm) * inv512 + w[511 + jj - ii];
            val = fmaxf(val, 0.0f);
            km[(size_t)b * NSEQ * NSEQ + (size_t)ii * NSEQ + jj] = f2bf(val * val);
        }
    }
}

// ---------------------------------------------------------------------------
// kernel @ V per batch (bf16 MFMA), gated by u in-place (u -> gated).
// A = km[b] [512][512], Bt = vT[b] [2048][512].
// ---------------------------------------------------------------------------
__global__ __launch_bounds__(256) void gemm_pv_mfma(const ushort* __restrict__ km,
                                                    const ushort* __restrict__ vT,
                                                    ushort* __restrict__ ug) {
    __shared__ ushort As[128 * 32], Bs[128 * 32];
    float4x acc[4][4] = {};
    const int b = blockIdx.z;
    const int n0 = blockIdx.x * 128, m0 = blockIdx.y * 128;
    mfma_core_128(km + (size_t)b * NSEQ * NSEQ, vT + (size_t)b * EDIM * NSEQ,
                  NSEQ, NSEQ, NSEQ, m0, n0, As, Bs, acc);
    const size_t tokbase = (size_t)b * NSEQ;
    epilogue_loop(acc, m0, n0, [&](int m, int n, float aval) {
        const size_t idx = (tokbase + m) * EDIM + n;
        ug[idx] = f2bf(bf2f(ug[idx]) * aval);
    });
}

// ---------------------------------------------------------------------------
// GEMM2: out = gated @ o_w + o_b + x (bf16 MFMA, fp32 epilogue/out).
// ---------------------------------------------------------------------------
__global__ __launch_bounds__(256) void gemm_out_mfma(const ushort* __restrict__ A,
                                                     const ushort* __restrict__ Bt,
                                                     const float* __restrict__ ob,
                                                     const float* __restrict__ x,
                                                     float* __restrict__ out) {
    __shared__ ushort As[128 * 32], Bs[128 * 32];
    float4x acc[4][4] = {};
    const int n0 = blockIdx.x * 128, m0 = blockIdx.y * 128;
    mfma_core_128(A, Bt, EDIM, EDIM, EDIM, m0, n0, As, Bs, acc);
    epilogue_loop(acc, m0, n0, [&](int m, int n, float aval) {
        out[(size_t)m * HIDDEN + n] = aval + ob[n] + x[(size_t)m * HIDDEN + n];
    });
}

// ---------------------------------------------------------------------------
// Workspace (bytes), per chunk of C batches (R = C*512 tokens):
//   xn bf16  : C*1048576   (dead after gemm_uv; overlay: q fp32 @+0 (C*262144),
//                           k fp32 @+C*262144, km bf16 @+C*524288 (C*524288))
//   u/gated  : C*2097152   bf16 (pv writes gated in-place)
//   vT bf16  : C*2097152
//   base fp32: C*262144
// fixed: sin/cos 131072*2, uv_wt bf16 8650752, o_wt bf16 4194304.
// need = C*5505024 + 13107200  (C=32: 189 MB).
// ---------------------------------------------------------------------------
extern "C" void kernel_launch(void* const* d_in, const int* in_sizes, int n_in,
                              void* d_out, int out_size, void* d_ws, size_t ws_size,
                              hipStream_t stream) {
    const float* x     = (const float*)d_in[0];
    const float* mask  = (const float*)d_in[1];
    const float* gamma = (const float*)d_in[2];
    const float* beta  = (const float*)d_in[3];
    const float* w     = (const float*)d_in[4];
    const float* uv_w  = (const float*)d_in[7];
    const float* uv_b  = (const float*)d_in[8];
    const float* o_w   = (const float*)d_in[9];
    const float* o_b   = (const float*)d_in[10];
    const float* ln_g  = (const float*)d_in[11];
    const float* ln_b  = (const float*)d_in[12];
    float* out = (float*)d_out;

    int C = 32;
    while (C > 1) {
        unsigned long long need = (unsigned long long)C * 5505024ull + 13107200ull;
        if (need <= (unsigned long long)ws_size) break;
        C >>= 1;
    }
    const int R = C * NSEQ;

    char* p = (char*)d_ws;
    ushort* xn  = (ushort*)p;  p += (size_t)C * 1048576;
    ushort* u   = (ushort*)p;  p += (size_t)C * 2097152;
    ushort* vT  = (ushort*)p;  p += (size_t)C * 2097152;
    float* base = (float*)p;   p += (size_t)C * 262144;
    float* sint = (float*)p;   p += 131072;
    float* cost = (float*)p;   p += 131072;
    ushort* uv_wt = (ushort*)p; p += 8650752;
    ushort* o_wt  = (ushort*)p; p += 4194304;
    float* q  = (float*)xn;
    float* k  = (float*)((char*)xn + (size_t)C * 262144);
    ushort* km = (ushort*)((char*)xn + (size_t)C * 524288);

    hipLaunchKernelGGL(tab_kernel, dim3(512), dim3(64), 0, stream, sint, cost);
    hipLaunchKernelGGL(transpose_f32_bf16, dim3(132, 32), dim3(256), 0, stream,
                       uv_w, uv_wt, HIDDEN, UVN);
    hipLaunchKernelGGL(transpose_f32_bf16, dim3(32, 64), dim3(256), 0, stream,
                       o_w, o_wt, EDIM, HIDDEN);

    for (int b0 = 0; b0 < BATCH; b0 += C) {
        const float* xc = x + (size_t)b0 * NSEQ * HIDDEN;
        float*       oc = out + (size_t)b0 * NSEQ * HIDDEN;
        const float* mc = mask + (size_t)b0 * NSEQ;
        hipLaunchKernelGGL(ln_kernel, dim3(R), dim3(256), 0, stream, xc, ln_g, ln_b, xn);
        hipLaunchKernelGGL(gemm_uv_mfma, dim3(33, R / 128), dim3(256), 0, stream,
                           xn, uv_wt, uv_b, u, vT, base);
        hipLaunchKernelGGL(rope_kernel, dim3(R), dim3(128), 0, stream,
                           base, gamma, beta, sint, cost, q, k);
        hipLaunchKernelGGL(gemm_qk, dim3(8, 8, C), dim3(256), 0, stream, q, k, mc, w, km);
        hipLaunchKernelGGL(gemm_pv_mfma, dim3(16, 4, C), dim3(256), 0, stream, km, vT, u);
        hipLaunchKernelGGL(gemm_out_mfma, dim3(8, R / 128), dim3(256), 0, stream,
                           u, o_wt, o_b, xc, oc);
    }
}